// Round 3
// baseline (609.085 us; speedup 1.0000x reference)
//
#include <hip/hip_runtime.h>
#include <math.h>

// Problem constants (from reference setup_inputs)
#define BNUM 16
#define NNUM 4096
#define DNUM 1024
#define CNUM 4
#define HNUM 512

#define SCH   64              // N-chunks per bag
#define ROWS  (NNUM / SCH)    // 64 rows per workgroup
#define RPW   (ROWS / 4)      // 16 rows per wave (4 waves / 256-thread block)

// Workspace layout (in floats):
//  partials: [BNUM*SCH] x PSTRIDE  {sum[1024], max[1024], acc[1024], m, l, pad}
//  Weff: [3*DNUM][4], bias[4], then counters (uint): [wctr, bagctr[16]]
#define PSTRIDE 3080
#define NPART   (BNUM * SCH)
#define XOFF    ((size_t)NPART * PSTRIDE)
#define WOFF    (XOFF + (size_t)BNUM * 3 * DNUM)
#define BIASOFF (WOFF + (size_t)3 * DNUM * 4)
#define CTRWOFF (BIASOFF + 8)

#define NWEFF   769           // 768 weff blocks + 1 bias block
#define NMAIN   (SCH * BNUM)  // 1024 mainpass blocks

#define NEG_INF (-__builtin_inff())

typedef float vf4 __attribute__((ext_vector_type(4)));

__device__ __forceinline__ void load_pair(const vf4* rowA, int lane,
                                          vf4 (&va)[4], vf4 (&vb)[4]) {
    const vf4* rowB = rowA + (DNUM / 4);
#pragma unroll
    for (int s = 0; s < 4; ++s) va[s] = __builtin_nontemporal_load(rowA + s * 64 + lane);
#pragma unroll
    for (int s = 0; s < 4; ++s) vb[s] = __builtin_nontemporal_load(rowB + s * 64 + lane);
}

__device__ __forceinline__ void process_pair(const vf4 (&va)[4], const vf4 (&vb)[4],
                                             const vf4 (&q)[4],
                                             vf4 (&sum)[4], vf4 (&mx)[4], vf4 (&acc)[4],
                                             float& m, float& l) {
    float pa = 0.f, pb = 0.f;
#pragma unroll
    for (int s = 0; s < 4; ++s) {
        pa += va[s].x * q[s].x + va[s].y * q[s].y + va[s].z * q[s].z + va[s].w * q[s].w;
        pb += vb[s].x * q[s].x + vb[s].y * q[s].y + vb[s].z * q[s].z + vb[s].w * q[s].w;
    }
#pragma unroll
    for (int off = 32; off; off >>= 1) {
        pa += __shfl_xor(pa, off, 64);
        pb += __shfl_xor(pb, off, 64);
    }
    // online softmax: wave-uniform, rarely-taken rescale
    const float mnew = fmaxf(m, fmaxf(pa, pb));
    if (mnew > m) {
        const float alpha = __expf(m - mnew);   // m=-inf first time -> 0
        l *= alpha;
#pragma unroll
        for (int s = 0; s < 4; ++s) acc[s] *= alpha;
        m = mnew;
    }
    const float wa = __expf(pa - m);
    const float wb = __expf(pb - m);
    l += wa + wb;
#pragma unroll
    for (int s = 0; s < 4; ++s) {
        sum[s] += va[s] + vb[s];
        mx[s].x = fmaxf(mx[s].x, fmaxf(va[s].x, vb[s].x));
        mx[s].y = fmaxf(mx[s].y, fmaxf(va[s].y, vb[s].y));
        mx[s].z = fmaxf(mx[s].z, fmaxf(va[s].z, vb[s].z));
        mx[s].w = fmaxf(mx[s].w, fmaxf(va[s].w, vb[s].w));
        acc[s] += wa * va[s] + wb * vb[s];
    }
}

// ---------------------------------------------------------------------------
// Fused kernel. Blocks [0,768): Weff = W1@W2 (4 rows/block). Block 768:
// bias = b1@W2 + b2. Blocks [769, 769+1024): streaming mainpass; the last
// chunk-block to finish a bag (device atomic counter) performs that bag's
// combine+head in-place, hidden under other bags' tails.
// ---------------------------------------------------------------------------
__global__ __launch_bounds__(256, 3) void k_fused(const float* __restrict__ bags,
                                                  const float* __restrict__ query,
                                                  const float* __restrict__ W1,
                                                  const float* __restrict__ b1,
                                                  const float* __restrict__ W2,
                                                  const float* __restrict__ b2,
                                                  float* __restrict__ ws,
                                                  float* __restrict__ out) {
    const int tid  = threadIdx.x;
    const int wave = tid >> 6;
    const int lane = tid & 63;
    unsigned int* ctrs = (unsigned int*)(ws + CTRWOFF);   // [0]=wctr, [1+b]=bag ctr

    __shared__ float buf[4][DNUM];        // 16 KiB combine buffer
    __shared__ float sm[4], sl[4];
    __shared__ int   isFin;
    __shared__ float eS[SCH];
    __shared__ float lbS;
    __shared__ float red[4][4];

    if (blockIdx.x < NWEFF) {
        // ------------------- Weff / bias path -------------------
        const vf4* w2 = (const vf4*)W2;
        if (blockIdx.x < 768) {
            const int k = blockIdx.x * 4 + wave;
            const float* r = W1 + (size_t)k * HNUM;
            float a0 = 0.f, a1 = 0.f, a2 = 0.f, a3 = 0.f;
#pragma unroll
            for (int t = 0; t < 8; ++t) {
                const int j = lane * 8 + t;
                const float wv = r[j];
                const vf4   w  = w2[j];
                a0 += wv * w.x; a1 += wv * w.y; a2 += wv * w.z; a3 += wv * w.w;
            }
#pragma unroll
            for (int off = 32; off; off >>= 1) {
                a0 += __shfl_xor(a0, off, 64);
                a1 += __shfl_xor(a1, off, 64);
                a2 += __shfl_xor(a2, off, 64);
                a3 += __shfl_xor(a3, off, 64);
            }
            if (lane == 0) {
                vf4 rv; rv.x = a0; rv.y = a1; rv.z = a2; rv.w = a3;
                ((vf4*)(ws + WOFF))[k] = rv;
            }
        } else if (wave == 0) {
            float a0 = 0.f, a1 = 0.f, a2 = 0.f, a3 = 0.f;
#pragma unroll
            for (int t = 0; t < 8; ++t) {
                const int j = lane * 8 + t;
                const float bv = b1[j];
                const vf4   w  = w2[j];
                a0 += bv * w.x; a1 += bv * w.y; a2 += bv * w.z; a3 += bv * w.w;
            }
#pragma unroll
            for (int off = 32; off; off >>= 1) {
                a0 += __shfl_xor(a0, off, 64);
                a1 += __shfl_xor(a1, off, 64);
                a2 += __shfl_xor(a2, off, 64);
                a3 += __shfl_xor(a3, off, 64);
            }
            if (lane == 0) {
                float* bias = ws + BIASOFF;
                bias[0] = a0 + b2[0]; bias[1] = a1 + b2[1];
                bias[2] = a2 + b2[2]; bias[3] = a3 + b2[3];
            }
        }
        __threadfence();
        __syncthreads();
        if (tid == 0) atomicAdd(&ctrs[0], 1u);
        return;
    }

    // ------------------- mainpass path -------------------
    const int v     = blockIdx.x - NWEFF;
    const int chunk = v & (SCH - 1);
    const int b     = v >> 6;

    const vf4* q4 = (const vf4*)query;
    vf4 q[4];
#pragma unroll
    for (int s = 0; s < 4; ++s) q[s] = q4[s * 64 + lane];

    vf4 sum[4], mx[4], acc[4];
#pragma unroll
    for (int s = 0; s < 4; ++s) {
        sum[s] = (vf4)0.f;
        acc[s] = (vf4)0.f;
        mx[s]  = (vf4)NEG_INF;
    }
    float m = NEG_INF, l = 0.f;

    const int n0 = chunk * ROWS + wave * RPW;
    const vf4* base = (const vf4*)(bags + (size_t)b * NNUM * DNUM);

    // software-pipelined: 4 rows (2 pairs) per iteration, ping-pong va/vb <-> na/nb
    vf4 va[4], vb[4], na[4], nb[4];
    load_pair(base + (size_t)n0 * (DNUM / 4), lane, va, vb);
    for (int r = 0; r < RPW; r += 4) {
        load_pair(base + (size_t)(n0 + r + 2) * (DNUM / 4), lane, na, nb);
        process_pair(va, vb, q, sum, mx, acc, m, l);
        if (r + 4 < RPW)
            load_pair(base + (size_t)(n0 + r + 4) * (DNUM / 4), lane, va, vb);
        process_pair(na, nb, q, sum, mx, acc, m, l);
    }

    // ---- block combine across 4 waves via reused 16KB LDS buffer ----
    if (lane == 0) { sm[wave] = m; sl[wave] = l; }

    float* wsp = ws + (size_t)(b * SCH + chunk) * PSTRIDE;

#pragma unroll
    for (int s = 0; s < 4; ++s) ((vf4*)(&buf[wave][s * 256]))[lane] = sum[s];
    __syncthreads();
    {
        vf4 a0 = ((vf4*)buf[0])[tid];
        vf4 a1 = ((vf4*)buf[1])[tid];
        vf4 a2 = ((vf4*)buf[2])[tid];
        vf4 a3 = ((vf4*)buf[3])[tid];
        ((vf4*)wsp)[tid] = a0 + a1 + a2 + a3;
    }
    __syncthreads();

#pragma unroll
    for (int s = 0; s < 4; ++s) ((vf4*)(&buf[wave][s * 256]))[lane] = mx[s];
    __syncthreads();
    {
        vf4 a0 = ((vf4*)buf[0])[tid];
        vf4 a1 = ((vf4*)buf[1])[tid];
        vf4 a2 = ((vf4*)buf[2])[tid];
        vf4 a3 = ((vf4*)buf[3])[tid];
        vf4 r;
        r.x = fmaxf(fmaxf(a0.x, a1.x), fmaxf(a2.x, a3.x));
        r.y = fmaxf(fmaxf(a0.y, a1.y), fmaxf(a2.y, a3.y));
        r.z = fmaxf(fmaxf(a0.z, a1.z), fmaxf(a2.z, a3.z));
        r.w = fmaxf(fmaxf(a0.w, a1.w), fmaxf(a2.w, a3.w));
        ((vf4*)(wsp + 1024))[tid] = r;
    }
    __syncthreads();

#pragma unroll
    for (int s = 0; s < 4; ++s) ((vf4*)(&buf[wave][s * 256]))[lane] = acc[s];
    __syncthreads();
    {
        const float m0 = sm[0], m1 = sm[1], m2 = sm[2], m3 = sm[3];
        const float mb = fmaxf(fmaxf(m0, m1), fmaxf(m2, m3));
        const float e0 = __expf(m0 - mb), e1 = __expf(m1 - mb);
        const float e2 = __expf(m2 - mb), e3 = __expf(m3 - mb);
        vf4 a0 = ((vf4*)buf[0])[tid];
        vf4 a1 = ((vf4*)buf[1])[tid];
        vf4 a2 = ((vf4*)buf[2])[tid];
        vf4 a3 = ((vf4*)buf[3])[tid];
        ((vf4*)(wsp + 2048))[tid] = a0 * e0 + a1 * e1 + a2 * e2 + a3 * e3;
        if (tid == 0) {
            wsp[3072] = mb;
            wsp[3073] = sl[0] * e0 + sl[1] * e1 + sl[2] * e2 + sl[3] * e3;
        }
    }

    // ---- release partial, elect finisher for this bag ----
    __threadfence();
    __syncthreads();
    if (tid == 0) {
        const unsigned old = atomicAdd(&ctrs[1 + b], 1u);
        int fin = (old == SCH - 1);
        if (fin) {
            // wait for Weff+bias (dispatched first; normally already done)
            while (__hip_atomic_load(&ctrs[0], __ATOMIC_ACQUIRE,
                                     __HIP_MEMORY_SCOPE_AGENT) < NWEFF)
                __builtin_amdgcn_s_sleep(4);
        }
        isFin = fin;
    }
    __syncthreads();
    if (!isFin) return;
    __threadfence();   // acquire: make all bags' partials + Weff visible

    // ------------------- finish (combine + head) for bag b -------------------
    const float* pbag = ws + (size_t)b * SCH * PSTRIDE;

    if (wave == 0) {
        const float* p = pbag + (size_t)lane * PSTRIDE;
        const float mlane = p[3072];
        const float llane = p[3073];
        float mb = mlane;
#pragma unroll
        for (int off = 32; off; off >>= 1) mb = fmaxf(mb, __shfl_xor(mb, off, 64));
        const float e = __expf(mlane - mb);
        float lb = llane * e;
#pragma unroll
        for (int off = 32; off; off >>= 1) lb += __shfl_xor(lb, off, 64);
        eS[lane] = e;
        if (lane == 0) lbS = lb;
    }
    __syncthreads();
    const float inv_lb = 1.f / lbS;

    vf4 fs = (vf4)0.f, fa = (vf4)0.f;
    vf4 fm = (vf4)NEG_INF;
    for (int c = 0; c < SCH; ++c) {
        const float* p = pbag + (size_t)c * PSTRIDE;
        const vf4 sv = ((const vf4*)p)[tid];
        const vf4 mv = ((const vf4*)(p + 1024))[tid];
        const vf4 av = ((const vf4*)(p + 2048))[tid];
        const float e = eS[c];
        fs += sv;
        fm.x = fmaxf(fm.x, mv.x); fm.y = fmaxf(fm.y, mv.y);
        fm.z = fmaxf(fm.z, mv.z); fm.w = fmaxf(fm.w, mv.w);
        fa += e * av;
    }

    const vf4* weff = (const vf4*)(ws + WOFF);
    float c0 = 0.f, c1 = 0.f, c2 = 0.f, c3 = 0.f;
    const float scm = 1.f / NNUM;
    const float xm[4] = { fs.x * scm, fs.y * scm, fs.z * scm, fs.w * scm };
    const float xx[4] = { fm.x, fm.y, fm.z, fm.w };
    const float xa[4] = { fa.x * inv_lb, fa.y * inv_lb, fa.z * inv_lb, fa.w * inv_lb };
#pragma unroll
    for (int k = 0; k < 4; ++k) {
        const vf4 w = weff[tid * 4 + k];
        c0 += xm[k] * w.x; c1 += xm[k] * w.y; c2 += xm[k] * w.z; c3 += xm[k] * w.w;
    }
#pragma unroll
    for (int k = 0; k < 4; ++k) {
        const vf4 w = weff[DNUM + tid * 4 + k];
        c0 += xx[k] * w.x; c1 += xx[k] * w.y; c2 += xx[k] * w.z; c3 += xx[k] * w.w;
    }
#pragma unroll
    for (int k = 0; k < 4; ++k) {
        const vf4 w = weff[2 * DNUM + tid * 4 + k];
        c0 += xa[k] * w.x; c1 += xa[k] * w.y; c2 += xa[k] * w.z; c3 += xa[k] * w.w;
    }
#pragma unroll
    for (int off = 32; off; off >>= 1) {
        c0 += __shfl_xor(c0, off, 64);
        c1 += __shfl_xor(c1, off, 64);
        c2 += __shfl_xor(c2, off, 64);
        c3 += __shfl_xor(c3, off, 64);
    }
    if (lane == 0) { red[wave][0] = c0; red[wave][1] = c1; red[wave][2] = c2; red[wave][3] = c3; }
    __syncthreads();
    if (tid < 4) {
        const float* bias = ws + BIASOFF;
        out[b * 4 + tid] = red[0][tid] + red[1][tid] + red[2][tid] + red[3][tid] + bias[tid];
    }
}

extern "C" void kernel_launch(void* const* d_in, const int* in_sizes, int n_in,
                              void* d_out, int out_size, void* d_ws, size_t ws_size,
                              hipStream_t stream) {
    const float* bags  = (const float*)d_in[0];
    const float* query = (const float*)d_in[1];
    const float* W1    = (const float*)d_in[2];
    const float* b1    = (const float*)d_in[3];
    const float* W2    = (const float*)d_in[4];
    const float* b2    = (const float*)d_in[5];
    float* out = (float*)d_out;
    float* ws  = (float*)d_ws;

    // zero the 17 device-scope counters (ws is re-poisoned to 0xAA each call)
    hipMemsetAsync(ws + CTRWOFF, 0, 17 * sizeof(unsigned int), stream);
    k_fused<<<NWEFF + NMAIN, 256, 0, stream>>>(bags, query, W1, b1, W2, b2, ws, out);
}

// Round 4
// 377.703 us; speedup vs baseline: 1.6126x; 1.6126x over previous
//
#include <hip/hip_runtime.h>
#include <math.h>

// Problem constants (from reference setup_inputs)
#define BNUM 16
#define NNUM 4096
#define DNUM 1024
#define CNUM 4
#define HNUM 512

#define SCH   32              // N-chunks per bag
#define ROWS  (NNUM / SCH)    // 128 rows per workgroup
#define RPW   (ROWS / 4)      // 32 rows per wave (4 waves / 256-thread block)

#define NMAIN (SCH * BNUM)    // 512 mainpass blocks
#define NWEFFBLK 768
#define GRID1 (NMAIN + NWEFFBLK + 1)

// Workspace layout (in floats):
//  partials: [NMAIN] x PSTRIDE  {sum[1024], max[1024], acc[1024], m, l, pad}
//  Weff: [3*DNUM][4], bias[4]
#define PSTRIDE 3080
#define XOFF    ((size_t)NMAIN * PSTRIDE)
#define WOFF    (XOFF + 16)
#define BIASOFF (WOFF + (size_t)3 * DNUM * 4)

#define NEG_INF (-__builtin_inff())

typedef float vf4 __attribute__((ext_vector_type(4)));

// ---------------------------------------------------------------------------
// Stage 1. Blocks [0,NMAIN): streaming mainpass (R2-proven inner loop).
// Blocks [NMAIN, NMAIN+768): Weff = W1@W2. Last block: bias = b1@W2 + b2.
// No cross-block communication — the kernel boundary before k_finish
// provides all coherence (no device fences!).
// ---------------------------------------------------------------------------
__global__ __launch_bounds__(256) void k_stage1(const float* __restrict__ bags,
                                                const float* __restrict__ query,
                                                const float* __restrict__ W1,
                                                const float* __restrict__ b1,
                                                const float* __restrict__ W2,
                                                const float* __restrict__ b2,
                                                float* __restrict__ ws) {
    const int tid  = threadIdx.x;
    const int wave = tid >> 6;
    const int lane = tid & 63;

    if (blockIdx.x >= NMAIN) {
        // ------------------- Weff / bias path -------------------
        const vf4* w2 = (const vf4*)W2;
        const int wb = blockIdx.x - NMAIN;
        if (wb < NWEFFBLK) {
            const int k = wb * 4 + wave;
            const float* r = W1 + (size_t)k * HNUM;
            float a0 = 0.f, a1 = 0.f, a2 = 0.f, a3 = 0.f;
#pragma unroll
            for (int t = 0; t < 8; ++t) {
                const int j = lane * 8 + t;
                const float wv = r[j];
                const vf4   w  = w2[j];
                a0 += wv * w.x; a1 += wv * w.y; a2 += wv * w.z; a3 += wv * w.w;
            }
#pragma unroll
            for (int off = 32; off; off >>= 1) {
                a0 += __shfl_xor(a0, off, 64);
                a1 += __shfl_xor(a1, off, 64);
                a2 += __shfl_xor(a2, off, 64);
                a3 += __shfl_xor(a3, off, 64);
            }
            if (lane == 0) {
                vf4 rv; rv.x = a0; rv.y = a1; rv.z = a2; rv.w = a3;
                ((vf4*)(ws + WOFF))[k] = rv;
            }
        } else if (wave == 0) {
            float a0 = 0.f, a1 = 0.f, a2 = 0.f, a3 = 0.f;
#pragma unroll
            for (int t = 0; t < 8; ++t) {
                const int j = lane * 8 + t;
                const float bv = b1[j];
                const vf4   w  = w2[j];
                a0 += bv * w.x; a1 += bv * w.y; a2 += bv * w.z; a3 += bv * w.w;
            }
#pragma unroll
            for (int off = 32; off; off >>= 1) {
                a0 += __shfl_xor(a0, off, 64);
                a1 += __shfl_xor(a1, off, 64);
                a2 += __shfl_xor(a2, off, 64);
                a3 += __shfl_xor(a3, off, 64);
            }
            if (lane == 0) {
                float* bias = ws + BIASOFF;
                bias[0] = a0 + b2[0]; bias[1] = a1 + b2[1];
                bias[2] = a2 + b2[2]; bias[3] = a3 + b2[3];
            }
        }
        return;
    }

    // ------------------- mainpass path -------------------
    const int chunk = blockIdx.x & (SCH - 1);
    const int b     = blockIdx.x >> 5;

    const vf4* q4 = (const vf4*)query;
    vf4 q[4];
#pragma unroll
    for (int s = 0; s < 4; ++s) q[s] = q4[s * 64 + lane];

    vf4 sum[4], mx[4], acc[4];
#pragma unroll
    for (int s = 0; s < 4; ++s) {
        sum[s] = (vf4)0.f;
        acc[s] = (vf4)0.f;
        mx[s]  = (vf4)NEG_INF;
    }
    float m = NEG_INF, l = 0.f;

    const int n0 = chunk * ROWS + wave * RPW;
    const vf4* base = (const vf4*)(bags + (size_t)b * NNUM * DNUM);

    for (int r = 0; r < RPW; r += 2) {
        const vf4* rowA = base + (size_t)(n0 + r) * (DNUM / 4);
        const vf4* rowB = rowA + (DNUM / 4);
        vf4 va[4], vb[4];
#pragma unroll
        for (int s = 0; s < 4; ++s) va[s] = rowA[s * 64 + lane];
#pragma unroll
        for (int s = 0; s < 4; ++s) vb[s] = rowB[s * 64 + lane];

        float pa = 0.f, pb = 0.f;
#pragma unroll
        for (int s = 0; s < 4; ++s) {
            pa += va[s].x * q[s].x + va[s].y * q[s].y + va[s].z * q[s].z + va[s].w * q[s].w;
            pb += vb[s].x * q[s].x + vb[s].y * q[s].y + vb[s].z * q[s].z + vb[s].w * q[s].w;
        }
#pragma unroll
        for (int off = 32; off; off >>= 1) {
            pa += __shfl_xor(pa, off, 64);
            pb += __shfl_xor(pb, off, 64);
        }

        // online softmax: wave-uniform, rarely-taken rescale
        const float mnew = fmaxf(m, fmaxf(pa, pb));
        if (mnew > m) {
            const float alpha = __expf(m - mnew);   // m=-inf first time -> 0
            l *= alpha;
#pragma unroll
            for (int s = 0; s < 4; ++s) acc[s] *= alpha;
            m = mnew;
        }
        const float wa = __expf(pa - m);
        const float wb = __expf(pb - m);
        l += wa + wb;

#pragma unroll
        for (int s = 0; s < 4; ++s) {
            sum[s] += va[s] + vb[s];
            mx[s].x = fmaxf(mx[s].x, fmaxf(va[s].x, vb[s].x));
            mx[s].y = fmaxf(mx[s].y, fmaxf(va[s].y, vb[s].y));
            mx[s].z = fmaxf(mx[s].z, fmaxf(va[s].z, vb[s].z));
            mx[s].w = fmaxf(mx[s].w, fmaxf(va[s].w, vb[s].w));
            acc[s] += wa * va[s] + wb * vb[s];
        }
    }

    // ---- block combine across 4 waves via reused 16KB LDS buffer ----
    __shared__ float buf[4][DNUM];
    __shared__ float sm[4], sl[4];
    if (lane == 0) { sm[wave] = m; sl[wave] = l; }

    float* wsp = ws + (size_t)(b * SCH + chunk) * PSTRIDE;

#pragma unroll
    for (int s = 0; s < 4; ++s) ((vf4*)(&buf[wave][s * 256]))[lane] = sum[s];
    __syncthreads();
    {
        vf4 a0 = ((vf4*)buf[0])[tid];
        vf4 a1 = ((vf4*)buf[1])[tid];
        vf4 a2 = ((vf4*)buf[2])[tid];
        vf4 a3 = ((vf4*)buf[3])[tid];
        ((vf4*)wsp)[tid] = a0 + a1 + a2 + a3;
    }
    __syncthreads();

#pragma unroll
    for (int s = 0; s < 4; ++s) ((vf4*)(&buf[wave][s * 256]))[lane] = mx[s];
    __syncthreads();
    {
        vf4 a0 = ((vf4*)buf[0])[tid];
        vf4 a1 = ((vf4*)buf[1])[tid];
        vf4 a2 = ((vf4*)buf[2])[tid];
        vf4 a3 = ((vf4*)buf[3])[tid];
        vf4 r;
        r.x = fmaxf(fmaxf(a0.x, a1.x), fmaxf(a2.x, a3.x));
        r.y = fmaxf(fmaxf(a0.y, a1.y), fmaxf(a2.y, a3.y));
        r.z = fmaxf(fmaxf(a0.z, a1.z), fmaxf(a2.z, a3.z));
        r.w = fmaxf(fmaxf(a0.w, a1.w), fmaxf(a2.w, a3.w));
        ((vf4*)(wsp + 1024))[tid] = r;
    }
    __syncthreads();

#pragma unroll
    for (int s = 0; s < 4; ++s) ((vf4*)(&buf[wave][s * 256]))[lane] = acc[s];
    __syncthreads();
    {
        const float m0 = sm[0], m1 = sm[1], m2 = sm[2], m3 = sm[3];
        const float mb = fmaxf(fmaxf(m0, m1), fmaxf(m2, m3));
        const float e0 = __expf(m0 - mb), e1 = __expf(m1 - mb);
        const float e2 = __expf(m2 - mb), e3 = __expf(m3 - mb);
        vf4 a0 = ((vf4*)buf[0])[tid];
        vf4 a1 = ((vf4*)buf[1])[tid];
        vf4 a2 = ((vf4*)buf[2])[tid];
        vf4 a3 = ((vf4*)buf[3])[tid];
        ((vf4*)(wsp + 2048))[tid] = a0 * e0 + a1 * e1 + a2 * e2 + a3 * e3;
        if (tid == 0) {
            wsp[3072] = mb;
            wsp[3073] = sl[0] * e0 + sl[1] * e1 + sl[2] * e2 + sl[3] * e3;
        }
    }
}

// ---------------------------------------------------------------------------
// Stage 2 (combine + head), spread over grid (BNUM, 4): block owns 256 d's
// of bag b. Merges the 32 chunk (m,l) pairs (redundantly per block), streams
// the partial slices for its d-range, dots with Weff rows, and atomicAdds
// its 4-channel contribution into zeroed d_out.
// ---------------------------------------------------------------------------
__global__ __launch_bounds__(256) void k_finish(const float* __restrict__ ws,
                                                float* __restrict__ out) {
    const int b    = blockIdx.x;
    const int dg   = blockIdx.y;
    const int tid  = threadIdx.x;
    const int wave = tid >> 6, lane = tid & 63;
    const int d    = dg * 256 + tid;

    __shared__ float eS[SCH];
    __shared__ float lbS;
    __shared__ float red[4][4];

    const float* pbag = ws + (size_t)b * SCH * PSTRIDE;

    if (wave == 0) {
        const float* p = pbag + (size_t)(lane & (SCH - 1)) * PSTRIDE;
        const float mlane = (lane < SCH) ? p[3072] : NEG_INF;
        const float llane = (lane < SCH) ? p[3073] : 0.f;
        float mb = mlane;
#pragma unroll
        for (int off = 32; off; off >>= 1) mb = fmaxf(mb, __shfl_xor(mb, off, 64));
        const float e = __expf(mlane - mb);
        float lb = llane * e;
#pragma unroll
        for (int off = 32; off; off >>= 1) lb += __shfl_xor(lb, off, 64);
        if (lane < SCH) eS[lane] = e;
        if (lane == 0) lbS = lb;
    }
    __syncthreads();
    const float inv_lb = 1.f / lbS;

    float fs = 0.f, fa = 0.f, fm = NEG_INF;
    for (int c = 0; c < SCH; ++c) {
        const float* p = pbag + (size_t)c * PSTRIDE;
        fs += p[d];
        fm = fmaxf(fm, p[1024 + d]);
        fa += eS[c] * p[2048 + d];
    }
    const float xm = fs * (1.f / NNUM);
    const float xa = fa * inv_lb;

    const vf4* weff = (const vf4*)(ws + WOFF);
    const vf4 w0 = weff[d];
    const vf4 w1 = weff[DNUM + d];
    const vf4 w2 = weff[2 * DNUM + d];
    float c0 = xm * w0.x + fm * w1.x + xa * w2.x;
    float c1 = xm * w0.y + fm * w1.y + xa * w2.y;
    float c2 = xm * w0.z + fm * w1.z + xa * w2.z;
    float c3 = xm * w0.w + fm * w1.w + xa * w2.w;
#pragma unroll
    for (int off = 32; off; off >>= 1) {
        c0 += __shfl_xor(c0, off, 64);
        c1 += __shfl_xor(c1, off, 64);
        c2 += __shfl_xor(c2, off, 64);
        c3 += __shfl_xor(c3, off, 64);
    }
    if (lane == 0) { red[wave][0] = c0; red[wave][1] = c1; red[wave][2] = c2; red[wave][3] = c3; }
    __syncthreads();
    if (tid < 4) {
        float v = red[0][tid] + red[1][tid] + red[2][tid] + red[3][tid];
        if (dg == 0) v += (ws + BIASOFF)[tid];
        atomicAdd(&out[b * 4 + tid], v);
    }
}

extern "C" void kernel_launch(void* const* d_in, const int* in_sizes, int n_in,
                              void* d_out, int out_size, void* d_ws, size_t ws_size,
                              hipStream_t stream) {
    const float* bags  = (const float*)d_in[0];
    const float* query = (const float*)d_in[1];
    const float* W1    = (const float*)d_in[2];
    const float* b1    = (const float*)d_in[3];
    const float* W2    = (const float*)d_in[4];
    const float* b2    = (const float*)d_in[5];
    float* out = (float*)d_out;
    float* ws  = (float*)d_ws;

    // d_out is poisoned 0xAA each call; k_finish accumulates atomically.
    hipMemsetAsync(out, 0, (size_t)out_size * sizeof(float), stream);
    k_stage1<<<GRID1,            256, 0, stream>>>(bags, query, W1, b1, W2, b2, ws);
    k_finish<<<dim3(BNUM, 4),    256, 0, stream>>>(ws, out);
}